// Round 7
// baseline (839.831 us; speedup 1.0000x reference)
//
#include <hip/hip_runtime.h>

// ---------------- problem constants ----------------
constexpr int NY = 100, NX = 200;
constexpr int PML = 35;
constexpr int NYP = 170, NXP = 270;          // padded grid
constexpr int S = 2, NREC = 100, NT = 300;
constexpr float DX = 10.0f, DT = 1e-3f, DT2 = DT * DT;

// tiling: 2 shots x 16x8 tiles -> 256 blocks (one per CU)
constexpr int NTY = 16, NTX = 8;
constexpr int TY = 11, TX = 34;              // nominal tile (last row/col smaller)
constexpr int NBLKS = S * NTY * NTX;         // 256
constexpr int THREADS = 384;                 // 1 cell/thread (374 cells max), 6 waves

// bank-perfect LDS strides: stride % 32 == 2 -> a 34+30 lane wave covers all
// 32 banks exactly twice (2-way aliasing is free on CDNA4)
constexpr int UW = 66;                       // u row stride (needs >= TX+16 = 50)
constexpr int UH = TY + 16;                  // 27
constexpr int PYH = TY + 8;                  // 19 rows; stride TX=34 (34%32==2)
constexpr int PXW = 66;                      // px row stride (needs >= cols+8 = 42)
constexpr int BXW = TX + 8;                  // 42 bx coefficient entries

// packed strips: each halo cell is 8B {float value, int tag} (single-copy atomic)
constexpr int CELLS_NS = 8 * TX;             // 272
constexpr int CELLS_WE = TY * 8;             // 88
constexpr int OFF_N = 0;
constexpr int OFF_S = CELLS_NS;              // 272
constexpr int OFF_W = 2 * CELLS_NS;          // 544
constexpr int OFF_E = 2 * CELLS_NS + CELLS_WE;  // 632
constexpr int STAGE_CELLS = 2 * CELLS_NS + 2 * CELLS_WE;  // 720 cells = 5760 B

typedef unsigned long long u64;

// stencil coefficients, offsets -4..4, pre-scaled by 1/dx^2 and 1/dx
__device__ __constant__ float C2D[9] = {
    (float)(-1.0/560.0/100.0), (float)(8.0/315.0/100.0), (float)(-1.0/5.0/100.0),
    (float)(8.0/5.0/100.0),    (float)(-205.0/72.0/100.0), (float)(8.0/5.0/100.0),
    (float)(-1.0/5.0/100.0),   (float)(8.0/315.0/100.0),  (float)(-1.0/560.0/100.0)};
__device__ __constant__ float C1D[9] = {
    (float)(1.0/280.0/10.0), (float)(-4.0/105.0/10.0), (float)(1.0/5.0/10.0),
    (float)(-4.0/5.0/10.0),  0.0f,                     (float)(4.0/5.0/10.0),
    (float)(-1.0/5.0/10.0),  (float)(4.0/105.0/10.0),  (float)(-1.0/280.0/10.0)};

// ---------------- agent-scope accessors (coherent at Infinity Cache) -------
__device__ __forceinline__ u64 gload64(const u64* p) {
    return __hip_atomic_load(p, __ATOMIC_RELAXED, __HIP_MEMORY_SCOPE_AGENT);
}
__device__ __forceinline__ void gstore64(u64* p, u64 v) {
    __hip_atomic_store(p, v, __ATOMIC_RELAXED, __HIP_MEMORY_SCOPE_AGENT);
}

__device__ __forceinline__ float sigma_of(int d, int n, float smax) {
    float r = fmaxf(fmaxf((float)(PML - d) / (float)PML,
                          (float)(d - (n - 1 - PML)) / (float)PML), 0.0f);
    return smax * r * r;
}

// ---------------- setup: vmax -> sigma_max ----------------
__global__ void vmax_kernel(const float* __restrict__ vp, float* __restrict__ cst) {
    __shared__ float red[256];
    float m = 0.0f;
    for (int i = threadIdx.x; i < NY * NX; i += 256) m = fmaxf(m, vp[i]);
    red[threadIdx.x] = m;
    __syncthreads();
    for (int s2 = 128; s2 > 0; s2 >>= 1) {
        if (threadIdx.x < s2) red[threadIdx.x] = fmaxf(red[threadIdx.x], red[threadIdx.x + s2]);
        __syncthreads();
    }
    if (threadIdx.x == 0)
        cst[0] = 3.0f * red[0] * logf(1000.0f) / (2.0f * PML * DX);
}

// ------- persistent kernel: single barrier/step, prefetched packed strips ---
__global__ __launch_bounds__(THREADS) void persist_kernel(
    const float* __restrict__ vp, const float* __restrict__ src,
    const int* __restrict__ src_loc, const int* __restrict__ rec_loc,
    float* __restrict__ out, u64* __restrict__ stage,
    const float* __restrict__ cst) {

    __shared__ float uS[2][UH * UW];       // u(t) / u(t-1)->u(t+1), swap each step
    __shared__ float pyS[2][PYH * TX];     // py double buffer (read old, write new)
    __shared__ float pxS[2][TY * PXW];     // px double buffer
    __shared__ float byS[PYH], bymS[PYH], bxS[BXW], bxmS[BXW];
    __shared__ float srcS[NT];             // this shot's source wavelet

    const int tid = threadIdx.x;
    const int bid = blockIdx.x;
    const int sh  = bid / (NTY * NTX);
    const int tr  = bid - sh * (NTY * NTX);
    const int tyi = tr / NTX, txi = tr - tyi * NTX;
    const int y0 = tyi * TY, x0 = txi * TX;
    const int rows = min(TY, NYP - y0), cols = min(TX, NXP - x0);
    const float smax = cst[0];

    // zero LDS state (domain-boundary halos stay 0 forever)
    for (int i = tid; i < 2 * UH * UW; i += THREADS) ((float*)uS)[i] = 0.0f;
    for (int i = tid; i < 2 * PYH * TX; i += THREADS) ((float*)pyS)[i] = 0.0f;
    for (int i = tid; i < 2 * TY * PXW; i += THREADS) ((float*)pxS)[i] = 0.0f;

    if (tid < PYH) {
        int yy = y0 - 4 + tid;
        if (yy >= 0 && yy < NYP) {
            float b = __expf(-sigma_of(yy, NYP, smax) * DT);
            byS[tid] = b; bymS[tid] = b - 1.0f;
        } else { byS[tid] = 0.0f; bymS[tid] = 0.0f; }
    }
    if (tid < BXW) {
        int xx = x0 - 4 + tid;
        if (xx >= 0 && xx < NXP) {
            float b = __expf(-sigma_of(xx, NXP, smax) * DT);
            bxS[tid] = b; bxmS[tid] = b - 1.0f;
        } else { bxS[tid] = 0.0f; bxmS[tid] = 0.0f; }
    }

    // per-thread cell (t-invariant): 1 cell per thread
    const bool hasTask = (tid < rows * cols);
    const int y = hasTask ? tid / cols : 0;
    const int x = hasTask ? tid - y * cols : 0;

    // per-thread t-invariant physics coefficients (registers, not LDS)
    float e_r = 0.0f, d_r = 0.0f, Av_r = 0.0f, Bv_r = 0.0f;
    if (hasTask) {
        int gy = y0 + y, gx = x0 + x;
        int vy = min(max(gy - PML, 0), NY - 1), vx = min(max(gx - PML, 0), NX - 1);
        float v = vp[vy * NX + vx];
        e_r = DT2 * v * v;
        float syv = sigma_of(gy, NYP, smax), sxv = sigma_of(gx, NXP, smax);
        d_r  = 1.0f / (1.0f + 0.5f * (syv + sxv) * DT);
        Av_r = 2.0f - syv * sxv * DT2;
        Bv_r = 1.0f - 0.5f * (syv + sxv) * DT;
    }

    // source (NSRC == 1 per shot); stage wavelet into LDS
    const int sy = src_loc[sh * 2 + 0] + PML, sx = src_loc[sh * 2 + 1] + PML;
    const bool ownSrc = (sy >= y0 && sy < y0 + rows && sx >= x0 && sx < x0 + cols);
    const bool isSrcThread = hasTask && ownSrc && (y == sy - y0) && (x == sx - x0);
    if (ownSrc)
        for (int i = tid; i < NT; i += THREADS) srcS[i] = src[sh * NT + i];

    // receiver: thread tid handles global receiver tid (<=1 per thread)
    int recLds = -1, recOut = 0;
    if (tid < S * NREC) {
        int rs = tid / NREC, rr2 = tid - rs * NREC;
        int ry = rec_loc[(rs * NREC + rr2) * 2 + 0] + PML;
        int rx = rec_loc[(rs * NREC + rr2) * 2 + 1] + PML;
        if (rs == sh && ry >= y0 && ry < y0 + rows && rx >= x0 && rx < x0 + cols) {
            recLds = (ry - y0 + 8) * UW + (rx - x0 + 8);
            recOut = rs * NT * NREC + rr2;
        }
    }

    const int bN = (tyi > 0)       ? bid - NTX : -1;
    const int bS = (tyi < NTY - 1) ? bid + NTX : -1;
    const int bW = (txi > 0)       ? bid - 1   : -1;
    const int bE = (txi < NTX - 1) ? bid + 1   : -1;

    const int nNS = 8 * cols, nWE = rows * 8;
    const int nTot = 2 * nNS + 2 * nWE;       // <= 720 <= 2*THREADS

    // ---- precompute the 2 halo-read descriptors per thread (t-invariant) ----
    int hLds[2]  = {-1, -1};    // LDS dest index
    int hSrc[2]  = {0, 0};      // cell index in stage (w/o parity term)
#pragma unroll
    for (int e = 0; e < 2; e++) {
        int i = tid + e * THREADS;
        if (i >= nTot) continue;
        int j = i, nb = -1, o = 0, lds = -1;
        if (j < nNS) {                         // from N neighbor's S strip
            nb = bN;
            int r2 = j / cols, c2 = j - r2 * cols;
            o = OFF_S + r2 * TX + c2;          // N nb always has rows==TY>=8
            lds = r2 * UW + 8 + c2;
        } else if ((j -= nNS) < nNS) {         // from S neighbor's N strip
            nb = bS;
            int r2 = j / cols, c2 = j - r2 * cols;
            if (nb >= 0) {
                int rowsS = min(TY, NYP - (y0 + TY));  // S nb row count
                if (r2 >= rowsS) nb = -1;      // out-of-domain: stays 0
            }
            o = OFF_N + r2 * TX + c2;
            lds = (8 + rows + r2) * UW + 8 + c2;
        } else if ((j -= nNS) < nWE) {         // from W neighbor's E strip
            nb = bW;
            o = OFF_E + j;
            lds = (8 + (j >> 3)) * UW + (j & 7);
        } else {                               // from E neighbor's W strip
            j -= nWE;
            nb = bE;
            o = OFF_W + j;
            lds = (8 + (j >> 3)) * UW + 8 + cols + (j & 7);
        }
        if (nb < 0) continue;
        hLds[e] = lds;
        hSrc[e] = nb * 2 * STAGE_CELLS + o;
    }
    const bool n0 = (hLds[0] >= 0), n1 = (hLds[1] >= 0);
    const u64* sA0 = stage + hSrc[0];
    const u64* sA1 = stage + hSrc[1];

    // ---- precompute strip-push cell offsets for own cell (t-invariant) ----
    int aN = -1, aS = -1, aW = -1, aE = -1;
    if (hasTask) {
        if (y < 8)          aN = OFF_N + y * TX + x;
        if (y >= rows - 8)  aS = OFF_S + (y - (rows - 8)) * TX + x;
        if (x < 8)          aW = OFF_W + y * 8 + x;
        if (x >= cols - 8)  aE = OFF_E + y * 8 + (x - (cols - 8));
    }

    // prologue: publish u(0)=0 cells with tag=1 into parity-0 slot
    {
        const u64 PK0 = ((u64)1 << 32);        // value bits 0.0f, tag 1
        u64* s0 = stage + (size_t)(bid * 2 + 0) * STAGE_CELLS;
        if (hasTask) {
            if (aN >= 0) gstore64(s0 + aN, PK0);
            if (aS >= 0) gstore64(s0 + aS, PK0);
            if (aW >= 0) gstore64(s0 + aW, PK0);
            if (aE >= 0) gstore64(s0 + aE, PK0);
        }
    }
    __syncthreads();

    // prefetch for t=0 (parity-0 slot)
    u64 pf0 = 0, pf1 = 0;
    if (n0) pf0 = gload64(sA0);
    if (n1) pf1 = gload64(sA1);

    float u_curr = 0.0f, u_prev = 0.0f;        // this cell's u(t), u(t-1)

    int pa = 0, pb = 0;
    for (int t = 0; t < NT; t++) {
        const int par = t & 1;                 // slot holding u(t) strips
        float* uCur = uS[pa];
        float* uN   = uS[pa ^ 1];
        const float* pyO = pyS[pb];
        float*       pyN = pyS[pb ^ 1];
        const float* pxO = pxS[pb];
        float*       pxN = pxS[pb ^ 1];

        // ---- 1. spin on prefetched packed cells; write halo to LDS ----
        if (n0 || n1) {
            const u64* s0 = sA0 + (size_t)par * STAGE_CELLS;
            const u64* s1 = sA1 + (size_t)par * STAGE_CELLS;
            for (;;) {
                bool ok0 = !n0 || (int)(pf0 >> 32) >= t + 1;
                bool ok1 = !n1 || (int)(pf1 >> 32) >= t + 1;
                if (ok0 && ok1) break;
                if (!ok0) pf0 = gload64(s0);
                if (!ok1) pf1 = gload64(s1);
            }
            if (n0) uCur[hLds[0]] = __uint_as_float((unsigned)pf0);
            if (n1) uCur[hLds[1]] = __uint_as_float((unsigned)pf1);
        }
        __syncthreads();                       // the ONLY barrier per step

        // ---- 2. receivers sample u(t) = un(t-1) ----
        if (t > 0 && recLds >= 0) out[recOut + (t - 1) * NREC] = uCur[recLds];

        // ---- 3. fused compute + early publish ----
        u64* sb = stage + (size_t)(bid * 2 + (par ^ 1)) * STAGE_CELLS;
        float unv = 0.0f, py0v = 0.0f, py4v = 0.0f, py8v = 0.0f;
        float px0v = 0.0f, px4v = 0.0f, px8v = 0.0f;
        if (hasTask) {
            // u column y-8..y+8 at col x; own cell from register
            float uc[17], ur[17];
#pragma unroll
            for (int j = 0; j < 17; j++)
                uc[j] = (j == 8) ? u_curr : uCur[(y + j) * UW + 8 + x];
#pragma unroll
            for (int k = 0; k < 17; k++)
                ur[k] = (k == 8) ? u_curr : uCur[(8 + y) * UW + x + k];

            // py_new at rows y-4..y+4 (redundant, in registers)
            float pyn[9], pxn[9];
#pragma unroll
            for (int j = 0; j < 9; j++) {
                float d1a = 0.0f, d1b = 0.0f;
#pragma unroll
                for (int k = 0; k < 4; k++) {
                    d1a = fmaf(C1D[k],     uc[j + k],     d1a);
                    d1b = fmaf(C1D[k + 5], uc[j + k + 5], d1b);
                }
                pyn[j] = fmaf(byS[y + j], pyO[(y + j) * TX + x],
                              bymS[y + j] * (d1a + d1b));
            }
#pragma unroll
            for (int j = 0; j < 9; j++) {
                float d1a = 0.0f, d1b = 0.0f;
#pragma unroll
                for (int k = 0; k < 4; k++) {
                    d1a = fmaf(C1D[k],     ur[j + k],     d1a);
                    d1b = fmaf(C1D[k + 5], ur[j + k + 5], d1b);
                }
                pxn[j] = fmaf(bxS[x + j], pxO[y * PXW + x + j],
                              bxmS[x + j] * (d1a + d1b));
            }

            float d2y = 0.0f, d2x = 0.0f, d1py = 0.0f, d1px = 0.0f;
#pragma unroll
            for (int k = 0; k < 9; k++) {
                d2y = fmaf(C2D[k], uc[4 + k], d2y);
                d2x = fmaf(C2D[k], ur[4 + k], d2x);
                if (k != 4) {
                    d1py = fmaf(C1D[k], pyn[k], d1py);
                    d1px = fmaf(C1D[k], pxn[k], d1px);
                }
            }
            const float lap = (d2y + d2x) + (d1py + d1px);
            const float f = isSrcThread ? srcS[t] : 0.0f;
            unv = (Av_r * u_curr - Bv_r * u_prev + e_r * (lap + f)) * d_r;

            // early packed publish: {u(t+1), tag=t+2} straight from register
            const u64 pk = ((u64)(unsigned)(t + 2) << 32) |
                           (u64)__float_as_uint(unv);
            if (aN >= 0) gstore64(sb + aN, pk);
            if (aS >= 0) gstore64(sb + aS, pk);
            if (aW >= 0) gstore64(sb + aW, pk);
            if (aE >= 0) gstore64(sb + aE, pk);

            py0v = pyn[0]; py4v = pyn[4]; py8v = pyn[8];
            px0v = pxn[0]; px4v = pxn[4]; px8v = pxn[8];
        }

        // ---- 4. prefetch next slot (overlaps MALL RT with LDS writes) ----
        if (n0) pf0 = gload64(sA0 + (size_t)(par ^ 1) * STAGE_CELLS);
        if (n1) pf1 = gload64(sA1 + (size_t)(par ^ 1) * STAGE_CELLS);

        // ---- 5. LDS state writes ----
        if (hasTask) {
            uN[(8 + y) * UW + 8 + x] = unv;
            pyN[(y + 4) * TX + x] = py4v;
            if (y < 4)         pyN[y * TX + x]       = py0v;
            if (y >= rows - 4) pyN[(y + 8) * TX + x] = py8v;
            pxN[y * PXW + (x + 4)] = px4v;
            if (x < 4)         pxN[y * PXW + x]       = px0v;
            if (x >= cols - 4) pxN[y * PXW + (x + 8)] = px8v;
            u_prev = u_curr; u_curr = unv;
        }

        pa ^= 1; pb ^= 1;
    }

    // epilogue: sample the last wavefield u(NT) = un(NT-1)
    __syncthreads();
    if (recLds >= 0) out[recOut + (NT - 1) * NREC] = uS[pa][recLds];
}

// ---------------- host launch ----------------
extern "C" void kernel_launch(void* const* d_in, const int* in_sizes, int n_in,
                              void* d_out, int out_size, void* d_ws, size_t ws_size,
                              hipStream_t stream) {
    const float* vp = (const float*)d_in[0];
    const float* src = (const float*)d_in[1];
    const int* src_loc = (const int*)d_in[2];
    const int* rec_loc = (const int*)d_in[3];
    float* out = (float*)d_out;

    float* ws = (float*)d_ws;
    float* cst = ws;                           // 32 floats (keeps stage 128B-aligned)
    u64* stage = (u64*)(ws + 32);              // NBLKS*2*STAGE_CELLS packed cells

    // zero cst + stage (tags=0 everywhere; prologue publishes tag=1 cells)
    hipMemsetAsync(d_ws, 0,
                   (size_t)32 * sizeof(float) +
                   (size_t)NBLKS * 2 * STAGE_CELLS * sizeof(u64),
                   stream);
    vmax_kernel<<<1, 256, 0, stream>>>(vp, cst);
    persist_kernel<<<NBLKS, THREADS, 0, stream>>>(
        vp, src, src_loc, rec_loc, out, stage, cst);
}